// Round 3
// baseline (531.120 us; speedup 1.0000x reference)
//
#include <hip/hip_runtime.h>

// ---------- helpers ----------
static __device__ __forceinline__ float bf2f(unsigned short u) {
    return __uint_as_float(((unsigned int)u) << 16);
}
static __device__ __forceinline__ unsigned short f2bf(float f) {
    unsigned int x = __float_as_uint(f);
    unsigned int lsb = (x >> 16) & 1u;
    x += 0x7fffu + lsb;                 // round-to-nearest-even
    return (unsigned short)(x >> 16);
}

// ---------- repack: fp32 weights -> bf16 fused QKV packs + fp32 biases ----------
// Wpack[inp][k][n], n = proj*256 + h*32 + e ; inp0=[e2p_Wq|p2e_Wk|p2e_Wv], inp1=[p2e_Wq|e2p_Wk|e2p_Wv]
// Wopack[dir][k][n] ; bias_pack[inp][768] fp32 ; bias2[dir][256] fp32
__global__ __launch_bounds__(256) void repack_kernel(
    const float* e2p_Wq, const float* e2p_bq,
    const float* e2p_Wk, const float* e2p_bk,
    const float* e2p_Wv, const float* e2p_bv,
    const float* e2p_Wo, const float* e2p_bo,
    const float* p2e_Wq, const float* p2e_bq,
    const float* p2e_Wk, const float* p2e_bk,
    const float* p2e_Wv, const float* p2e_bv,
    const float* p2e_Wo, const float* p2e_bo,
    unsigned short* Wpack, unsigned short* Wopack, float* bias_pack, float* bias2)
{
    int idx = blockIdx.x * 256 + threadIdx.x;
    const int WP = 2 * 256 * 768;
    if (idx < WP) {
        int inp = idx / (256 * 768);
        int rem = idx % (256 * 768);
        int k = rem / 768, n = rem % 768;
        int proj = n / 256, h = (n % 256) / 32, e = n % 32;
        const float* W;
        if (inp == 0) W = (proj == 0) ? e2p_Wq : (proj == 1) ? p2e_Wk : p2e_Wv;
        else          W = (proj == 0) ? p2e_Wq : (proj == 1) ? e2p_Wk : e2p_Wv;
        Wpack[idx] = f2bf(W[h * 8192 + k * 32 + e]);   // W[h][d=k][e], strides (8192,32,1)
    }
    int idx2 = idx - WP;
    if (idx2 >= 0 && idx2 < 2 * 65536) {
        int dir = idx2 / 65536, r = idx2 % 65536;
        Wopack[idx2] = f2bf((dir == 0 ? e2p_Wo : p2e_Wo)[r]);
    }
    if (idx < 1536) {
        int inp = idx / 768, n = idx % 768;
        int proj = n / 256, he = n % 256;
        const float* bsrc;
        if (inp == 0) bsrc = (proj == 0) ? e2p_bq : (proj == 1) ? p2e_bk : p2e_bv;
        else          bsrc = (proj == 0) ? p2e_bq : (proj == 1) ? e2p_bk : e2p_bv;
        bias_pack[idx] = bsrc[he];
    }
    if (idx >= 1536 && idx < 2048) {
        int j = idx - 1536;
        int dir = j / 256, n = j % 256;
        bias2[j] = (dir == 0 ? e2p_bo : p2e_bo)[n];
    }
}

// ---------- tiled GEMM: C[M x N] = A(M x 256) @ B(256 x N, bf16) + bias(fp32) ----------
// A dtype / C dtype selected by template. 64x64 tile, 256 threads, 4x4 micro-tile, K-chunk 32.
template<bool A_BF16, bool C_F32>
__global__ __launch_bounds__(256) void gemm_bias_kernel(
    const void* __restrict__ A0v, const void* __restrict__ A1v,
    const unsigned short* __restrict__ B0, const unsigned short* __restrict__ B1,
    const float* __restrict__ bias0, const float* __restrict__ bias1,
    void* __restrict__ C0v, void* __restrict__ C1v,
    int N)
{
    __shared__ __align__(16) float As[32][68];   // [k][m], padded row stride 68
    __shared__ __align__(16) float Bs[32][68];   // [k][n]

    const int z = blockIdx.z;
    const void* Av = z ? A1v : A0v;
    const unsigned short* B = z ? B1 : B0;
    const float* bias = z ? bias1 : bias0;
    void* Cv = z ? C1v : C0v;

    const int tid = threadIdx.x;
    const int tx = tid & 15, ty = tid >> 4;
    const long m0 = (long)blockIdx.y * 64;
    const int n0 = blockIdx.x * 64;

    const int ar = tid >> 2;            // 0..63 : A tile row
    const int ak = (tid & 3) * 8;       // 0,8,16,24 : A k offset
    const int bk = tid >> 3;            // 0..31 : B k row
    const int bn = (tid & 7) * 8;       // 0..56 : B n offset

    float acc[4][4] = {};

    for (int kb = 0; kb < 256; kb += 32) {
        float av[8];
        unsigned short bp[8];
        if (A_BF16) {
            unsigned short ap[8];
            __builtin_memcpy(ap, (const unsigned short*)Av + (m0 + ar) * 256 + kb + ak, 16);
            #pragma unroll
            for (int j = 0; j < 8; ++j) av[j] = bf2f(ap[j]);
        } else {
            __builtin_memcpy(av, (const float*)Av + (m0 + ar) * 256 + kb + ak, 32);
        }
        __builtin_memcpy(bp, B + (long)(kb + bk) * N + n0 + bn, 16);
        __syncthreads();   // protect previous iteration's LDS reads
        #pragma unroll
        for (int j = 0; j < 8; ++j) As[ak + j][ar] = av[j];
        #pragma unroll
        for (int j = 0; j < 8; ++j) Bs[bk][bn + j] = bf2f(bp[j]);
        __syncthreads();
        #pragma unroll
        for (int kk = 0; kk < 32; ++kk) {
            float a0 = As[kk][ty * 4 + 0], a1 = As[kk][ty * 4 + 1];
            float a2 = As[kk][ty * 4 + 2], a3 = As[kk][ty * 4 + 3];
            float b0 = Bs[kk][tx * 4 + 0], b1 = Bs[kk][tx * 4 + 1];
            float b2 = Bs[kk][tx * 4 + 2], b3 = Bs[kk][tx * 4 + 3];
            acc[0][0] += a0 * b0; acc[0][1] += a0 * b1; acc[0][2] += a0 * b2; acc[0][3] += a0 * b3;
            acc[1][0] += a1 * b0; acc[1][1] += a1 * b1; acc[1][2] += a1 * b2; acc[1][3] += a1 * b3;
            acc[2][0] += a2 * b0; acc[2][1] += a2 * b1; acc[2][2] += a2 * b2; acc[2][3] += a2 * b3;
            acc[3][0] += a3 * b0; acc[3][1] += a3 * b1; acc[3][2] += a3 * b2; acc[3][3] += a3 * b3;
        }
    }

    float bj[4];
    #pragma unroll
    for (int j = 0; j < 4; ++j) bj[j] = bias[n0 + tx * 4 + j];
    #pragma unroll
    for (int i = 0; i < 4; ++i) {
        long m = m0 + ty * 4 + i;
        if (C_F32) {
            float ov[4];
            #pragma unroll
            for (int j = 0; j < 4; ++j) ov[j] = acc[i][j] + bj[j];
            __builtin_memcpy((float*)Cv + m * N + n0 + tx * 4, ov, 16);
        } else {
            unsigned short ov[4];
            #pragma unroll
            for (int j = 0; j < 4; ++j) ov[j] = f2bf(acc[i][j] + bj[j]);
            __builtin_memcpy((unsigned short*)Cv + m * N + n0 + tx * 4, ov, 8);
        }
    }
}

// ---------- windowed cross-attention (one batch) ----------
// Y[inp][2048][768]: [0:256]=Q, [256:512]=K, [512:768]=V (bf16). Block per (s,dir).
// 256 threads = 8 heads x 32 lanes(e). OOB window positions use bias vectors (bk/bv), NOT masked.
__global__ __launch_bounds__(256) void attn_kernel(
    const unsigned short* __restrict__ Y, const float* __restrict__ bias_pack,
    unsigned short* __restrict__ att)
{
    const int s = blockIdx.x, dir = blockIdx.y;
    const int tid = threadIdx.x;
    const int h = tid >> 5, e = tid & 31;
    const int kvinp = 1 - dir;

    const float q = bf2f(Y[((long)dir * 2048 + s) * 768 + h * 32 + e]);
    const float* bkv = bias_pack + kvinp * 768;
    const float bk_e = bkv[256 + h * 32 + e];
    const float bv_e = bkv[512 + h * 32 + e];
    const long kvbase = (long)kvinp * 2048 * 768;

    float myscore = -3.0e38f;
    #pragma unroll
    for (int w = 0; w < 31; ++w) {
        int kv_s = s + w - 15;
        bool inr = (kv_s >= 0) && (kv_s < 2048);
        float kval = inr ? bf2f(Y[kvbase + (long)kv_s * 768 + 256 + h * 32 + e]) : bk_e;
        float part = q * kval;
        #pragma unroll
        for (int off = 16; off; off >>= 1) part += __shfl_xor(part, off, 32);
        if (e == w) myscore = part * 0.17677669529663687f;  // 1/sqrt(32)
    }

    float mval = myscore;
    #pragma unroll
    for (int off = 16; off; off >>= 1) mval = fmaxf(mval, __shfl_xor(mval, off, 32));

    float psum = 0.f, out = 0.f;
    #pragma unroll
    for (int w = 0; w < 31; ++w) {
        float sw = __shfl(myscore, w, 32);
        float p = __expf(sw - mval);
        psum += p;
        int kv_s = s + w - 15;
        bool inr = (kv_s >= 0) && (kv_s < 2048);
        float vval = inr ? bf2f(Y[kvbase + (long)kv_s * 768 + 512 + h * 32 + e]) : bv_e;
        out += p * vval;
    }

    att[((long)dir * 2048 + s) * 256 + h * 32 + e] = f2bf(out / psum);
}

// ---------- launch ----------
extern "C" void kernel_launch(void* const* d_in, const int* in_sizes, int n_in,
                              void* d_out, int out_size, void* d_ws, size_t ws_size,
                              hipStream_t stream)
{
    const float* eeg = (const float*)d_in[0];
    const float* pps = (const float*)d_in[1];
    float* out = (float*)d_out;

    char* ws = (char*)d_ws;
    unsigned short* Wpack   = (unsigned short*)(ws + 0);          // 2*256*768 bf16 = 786432 B
    unsigned short* Wopack  = (unsigned short*)(ws + 786432);     // 2*65536 bf16   = 262144 B
    float*          biasP   = (float*)(ws + 1048576);             // 1536 f32       = 6144 B
    float*          bias2   = (float*)(ws + 1054720);             // 512 f32        = 2048 B
    unsigned short* Yb      = (unsigned short*)(ws + 1056768);    // 2*2048*768 bf16 = 6291456 B
    unsigned short* attb    = (unsigned short*)(ws + 7348224);    // 2*2048*256 bf16 = 2097152 B
    // total: 9,445,376 B (~9.0 MB)

    repack_kernel<<<2048, 256, 0, stream>>>(
        (const float*)d_in[2],  (const float*)d_in[3],
        (const float*)d_in[4],  (const float*)d_in[5],
        (const float*)d_in[6],  (const float*)d_in[7],
        (const float*)d_in[8],  (const float*)d_in[9],
        (const float*)d_in[10], (const float*)d_in[11],
        (const float*)d_in[12], (const float*)d_in[13],
        (const float*)d_in[14], (const float*)d_in[15],
        (const float*)d_in[16], (const float*)d_in[17],
        Wpack, Wopack, biasP, bias2);

    for (int b = 0; b < 4; ++b) {
        const long boff = (long)b * 2048 * 256;   // per-batch element offset

        // fused QKV projection: [eeg_b|pps_b](2048x256 fp32) @ Wpack(256x768 bf16) + bias -> Yb (bf16)
        gemm_bias_kernel<false, false><<<dim3(12, 32, 2), 256, 0, stream>>>(
            eeg + boff, pps + boff, Wpack, Wpack + 196608, biasP, biasP + 768,
            Yb, Yb + 2048 * 768, 768);

        // windowed attention for batch b -> attb (bf16, [dir][2048][256])
        attn_kernel<<<dim3(2048, 2), 256, 0, stream>>>(Yb, biasP, attb);

        // output projection: attb(bf16) @ Wo(bf16) + bo -> d_out (fp32)
        gemm_bias_kernel<true, true><<<dim3(4, 32, 2), 256, 0, stream>>>(
            attb, attb + 2048 * 256, Wopack, Wopack + 65536, bias2, bias2 + 256,
            out + boff, out + 2097152 + boff, 256);
    }
}

// Round 4
// 235.098 us; speedup vs baseline: 2.2591x; 2.2591x over previous
//
#include <hip/hip_runtime.h>

// ---------- helpers ----------
static __device__ __forceinline__ float bf2f(unsigned short u) {
    return __uint_as_float(((unsigned int)u) << 16);
}
static __device__ __forceinline__ unsigned short f2bf(float f) {
    unsigned int x = __float_as_uint(f);
    unsigned int lsb = (x >> 16) & 1u;
    x += 0x7fffu + lsb;                 // round-to-nearest-even
    return (unsigned short)(x >> 16);
}

// ---------- repack: fp32 weights -> bf16 fused QKV packs + fp32 biases ----------
// Wpack[inp][k][n], n = proj*256 + h*32 + e ; inp0=[e2p_Wq|p2e_Wk|p2e_Wv], inp1=[p2e_Wq|e2p_Wk|e2p_Wv]
// Wopack[dir][k][n] ; bias_pack[inp][768] fp32 ; bias2[dir][256] fp32
__global__ __launch_bounds__(256) void repack_kernel(
    const float* e2p_Wq, const float* e2p_bq,
    const float* e2p_Wk, const float* e2p_bk,
    const float* e2p_Wv, const float* e2p_bv,
    const float* e2p_Wo, const float* e2p_bo,
    const float* p2e_Wq, const float* p2e_bq,
    const float* p2e_Wk, const float* p2e_bk,
    const float* p2e_Wv, const float* p2e_bv,
    const float* p2e_Wo, const float* p2e_bo,
    unsigned short* Wpack, unsigned short* Wopack, float* bias_pack, float* bias2)
{
    int idx = blockIdx.x * 256 + threadIdx.x;
    const int WP = 2 * 256 * 768;
    if (idx < WP) {
        int inp = idx / (256 * 768);
        int rem = idx % (256 * 768);
        int k = rem / 768, n = rem % 768;
        int proj = n / 256, h = (n % 256) / 32, e = n % 32;
        const float* W;
        if (inp == 0) W = (proj == 0) ? e2p_Wq : (proj == 1) ? p2e_Wk : p2e_Wv;
        else          W = (proj == 0) ? p2e_Wq : (proj == 1) ? e2p_Wk : e2p_Wv;
        Wpack[idx] = f2bf(W[h * 8192 + k * 32 + e]);   // W[h][d=k][e], strides (8192,32,1)
    }
    int idx2 = idx - WP;
    if (idx2 >= 0 && idx2 < 2 * 65536) {
        int dir = idx2 / 65536, r = idx2 % 65536;
        Wopack[idx2] = f2bf((dir == 0 ? e2p_Wo : p2e_Wo)[r]);
    }
    if (idx < 1536) {
        int inp = idx / 768, n = idx % 768;
        int proj = n / 256, he = n % 256;
        const float* bsrc;
        if (inp == 0) bsrc = (proj == 0) ? e2p_bq : (proj == 1) ? p2e_bk : p2e_bv;
        else          bsrc = (proj == 0) ? p2e_bq : (proj == 1) ? e2p_bk : e2p_bv;
        bias_pack[idx] = bsrc[he];
    }
    if (idx >= 1536 && idx < 2048) {
        int j = idx - 1536;
        int dir = j / 256, n = j % 256;
        bias2[j] = (dir == 0 ? e2p_bo : p2e_bo)[n];
    }
}

// ---------- tiled GEMM: C[M x N] = A(M x 256) @ B(256 x N, bf16) + bias(fp32) ----------
// A dtype / C dtype selected by template. 64x64 tile, 256 threads, 4x4 micro-tile, K-chunk 32.
template<bool A_BF16, bool C_F32>
__global__ __launch_bounds__(256) void gemm_bias_kernel(
    const void* __restrict__ A0v, const void* __restrict__ A1v,
    const unsigned short* __restrict__ B0, const unsigned short* __restrict__ B1,
    const float* __restrict__ bias0, const float* __restrict__ bias1,
    void* __restrict__ C0v, void* __restrict__ C1v,
    int N)
{
    __shared__ __align__(16) float As[32][68];   // [k][m], padded row stride 68
    __shared__ __align__(16) float Bs[32][68];   // [k][n]

    const int z = blockIdx.z;
    const void* Av = z ? A1v : A0v;
    const unsigned short* B = z ? B1 : B0;
    const float* bias = z ? bias1 : bias0;
    void* Cv = z ? C1v : C0v;

    const int tid = threadIdx.x;
    const int tx = tid & 15, ty = tid >> 4;
    const long m0 = (long)blockIdx.y * 64;
    const int n0 = blockIdx.x * 64;

    const int ar = tid >> 2;            // 0..63 : A tile row
    const int ak = (tid & 3) * 8;       // 0,8,16,24 : A k offset
    const int bk = tid >> 3;            // 0..31 : B k row
    const int bn = (tid & 7) * 8;       // 0..56 : B n offset

    float acc[4][4] = {};

    for (int kb = 0; kb < 256; kb += 32) {
        float av[8];
        unsigned short bp[8];
        if (A_BF16) {
            unsigned short ap[8];
            __builtin_memcpy(ap, (const unsigned short*)Av + (m0 + ar) * 256 + kb + ak, 16);
            #pragma unroll
            for (int j = 0; j < 8; ++j) av[j] = bf2f(ap[j]);
        } else {
            __builtin_memcpy(av, (const float*)Av + (m0 + ar) * 256 + kb + ak, 32);
        }
        __builtin_memcpy(bp, B + (long)(kb + bk) * N + n0 + bn, 16);
        __syncthreads();   // protect previous iteration's LDS reads
        #pragma unroll
        for (int j = 0; j < 8; ++j) As[ak + j][ar] = av[j];
        #pragma unroll
        for (int j = 0; j < 8; ++j) Bs[bk][bn + j] = bf2f(bp[j]);
        __syncthreads();
        #pragma unroll
        for (int kk = 0; kk < 32; ++kk) {
            float a0 = As[kk][ty * 4 + 0], a1 = As[kk][ty * 4 + 1];
            float a2 = As[kk][ty * 4 + 2], a3 = As[kk][ty * 4 + 3];
            float b0 = Bs[kk][tx * 4 + 0], b1 = Bs[kk][tx * 4 + 1];
            float b2 = Bs[kk][tx * 4 + 2], b3 = Bs[kk][tx * 4 + 3];
            acc[0][0] += a0 * b0; acc[0][1] += a0 * b1; acc[0][2] += a0 * b2; acc[0][3] += a0 * b3;
            acc[1][0] += a1 * b0; acc[1][1] += a1 * b1; acc[1][2] += a1 * b2; acc[1][3] += a1 * b3;
            acc[2][0] += a2 * b0; acc[2][1] += a2 * b1; acc[2][2] += a2 * b2; acc[2][3] += a2 * b3;
            acc[3][0] += a3 * b0; acc[3][1] += a3 * b1; acc[3][2] += a3 * b2; acc[3][3] += a3 * b3;
        }
    }

    float bj[4];
    #pragma unroll
    for (int j = 0; j < 4; ++j) bj[j] = bias[n0 + tx * 4 + j];
    #pragma unroll
    for (int i = 0; i < 4; ++i) {
        long m = m0 + ty * 4 + i;
        if (C_F32) {
            float ov[4];
            #pragma unroll
            for (int j = 0; j < 4; ++j) ov[j] = acc[i][j] + bj[j];
            __builtin_memcpy((float*)Cv + m * N + n0 + tx * 4, ov, 16);
        } else {
            unsigned short ov[4];
            #pragma unroll
            for (int j = 0; j < 4; ++j) ov[j] = f2bf(acc[i][j] + bj[j]);
            __builtin_memcpy((unsigned short*)Cv + m * N + n0 + tx * 4, ov, 8);
        }
    }
}

// ---------- windowed cross-attention, register-resident, all batches ----------
// Y[inp][8192][768]: [0:256]=Q, [256:512]=K, [512:768]=V (bf16), rows m = b*2048+s.
// Block = (s_tile of 32, b, dir); 256 threads = 32 s x 8 h. Each thread owns one (s,h):
// q[32], 31 scores, softmax, o[32] all in registers; K/V tile staged in LDS as bf16 pairs.
// OOB window positions use bias vectors (bk/bv), NOT masked (reference pads kv BEFORE projection).
#define ATT_TS 32
#define ATT_ROWS 62            // TS + 30
#define ATT_STRIDE 132         // pairs (128 + 4 pad), keeps rows 16B aligned
__global__ __launch_bounds__(256) void attn_kernel(
    const unsigned short* __restrict__ Y, const float* __restrict__ bias_pack,
    unsigned short* __restrict__ att)
{
    __shared__ unsigned int Ks[ATT_ROWS][ATT_STRIDE];
    __shared__ unsigned int Vs[ATT_ROWS][ATT_STRIDE];

    const int s0 = blockIdx.x * ATT_TS;
    const int b = blockIdx.y, dir = blockIdx.z;
    const int kvinp = 1 - dir;
    const int tid = threadIdx.x;

    const float* bkv = bias_pack + kvinp * 768;
    const long kvbase = ((long)kvinp * 8192 + b * 2048) * 768;

    // ---- stage K/V rows [s0-15, s0+46] ----
    {
        const int c = (tid & 31) * 4;           // pair index within row (4 pairs = 8 bf16 = 16B)
        for (int r = tid >> 5; r < ATT_ROWS; r += 8) {
            int p = s0 - 15 + r;
            unsigned int kq[4], vq[4];
            if (p >= 0 && p < 2048) {
                __builtin_memcpy(kq, Y + kvbase + (long)p * 768 + 256 + c * 2, 16);
                __builtin_memcpy(vq, Y + kvbase + (long)p * 768 + 512 + c * 2, 16);
            } else {
                unsigned short kb8[8], vb8[8];
                #pragma unroll
                for (int j = 0; j < 8; ++j) kb8[j] = f2bf(bkv[256 + c * 2 + j]);
                #pragma unroll
                for (int j = 0; j < 8; ++j) vb8[j] = f2bf(bkv[512 + c * 2 + j]);
                __builtin_memcpy(kq, kb8, 16);
                __builtin_memcpy(vq, vb8, 16);
            }
            __builtin_memcpy(&Ks[r][c], kq, 16);
            __builtin_memcpy(&Vs[r][c], vq, 16);
        }
    }

    // ---- load q (32 elems) into registers ----
    const int h = tid & 7, sl = tid >> 3;
    float q[32];
    {
        unsigned short qr[32];
        __builtin_memcpy(qr, Y + ((long)dir * 8192 + b * 2048 + s0 + sl) * 768 + h * 32, 64);
        #pragma unroll
        for (int j = 0; j < 32; ++j) q[j] = bf2f(qr[j]);
    }
    __syncthreads();

    // ---- scores: 31 independent 32-length dots from LDS ----
    const int hp = h * 16;                       // pair offset within row
    float sc[31];
    for (int w = 0; w < 31; ++w) {
        float dot = 0.f;
        #pragma unroll
        for (int jp = 0; jp < 16; ++jp) {
            unsigned int u = Ks[sl + w][hp + jp];
            dot += q[2 * jp]     * bf2f((unsigned short)(u & 0xffffu));
            dot += q[2 * jp + 1] * bf2f((unsigned short)(u >> 16));
        }
        sc[w] = dot * 0.17677669529663687f;      // 1/sqrt(32)
    }

    // ---- softmax in registers ----
    float mval = sc[0];
    #pragma unroll
    for (int w = 1; w < 31; ++w) mval = fmaxf(mval, sc[w]);
    float psum = 0.f;
    #pragma unroll
    for (int w = 0; w < 31; ++w) { sc[w] = __expf(sc[w] - mval); psum += sc[w]; }

    // ---- PV accumulate ----
    float o[32] = {};
    for (int w = 0; w < 31; ++w) {
        float pw = sc[w];
        #pragma unroll
        for (int jp = 0; jp < 16; ++jp) {
            unsigned int u = Vs[sl + w][hp + jp];
            o[2 * jp]     += pw * bf2f((unsigned short)(u & 0xffffu));
            o[2 * jp + 1] += pw * bf2f((unsigned short)(u >> 16));
        }
    }

    const float rs = 1.f / psum;
    unsigned short ov[32];
    #pragma unroll
    for (int j = 0; j < 32; ++j) ov[j] = f2bf(o[j] * rs);
    __builtin_memcpy(att + ((long)dir * 8192 + b * 2048 + s0 + sl) * 256 + h * 32, ov, 64);
}

// ---------- launch ----------
extern "C" void kernel_launch(void* const* d_in, const int* in_sizes, int n_in,
                              void* d_out, int out_size, void* d_ws, size_t ws_size,
                              hipStream_t stream)
{
    const float* eeg = (const float*)d_in[0];
    const float* pps = (const float*)d_in[1];
    float* out = (float*)d_out;

    char* ws = (char*)d_ws;
    unsigned short* Wpack   = (unsigned short*)(ws + 0);          // 2*256*768 bf16 = 786432 B
    unsigned short* Wopack  = (unsigned short*)(ws + 786432);     // 2*65536 bf16   = 262144 B
    float*          biasP   = (float*)(ws + 1048576);             // 1536 f32       = 6144 B
    float*          bias2   = (float*)(ws + 1054720);             // 512 f32        = 2048 B
    unsigned short* Y       = (unsigned short*)(ws + 1056768);    // 2*8192*768 bf16 = 25165824 B
    unsigned short* att     = (unsigned short*)(ws + 26222592);   // 2*8192*256 bf16 = 8388608 B
    // total: 34,611,200 B (~33 MB)

    repack_kernel<<<2048, 256, 0, stream>>>(
        (const float*)d_in[2],  (const float*)d_in[3],
        (const float*)d_in[4],  (const float*)d_in[5],
        (const float*)d_in[6],  (const float*)d_in[7],
        (const float*)d_in[8],  (const float*)d_in[9],
        (const float*)d_in[10], (const float*)d_in[11],
        (const float*)d_in[12], (const float*)d_in[13],
        (const float*)d_in[14], (const float*)d_in[15],
        (const float*)d_in[16], (const float*)d_in[17],
        Wpack, Wopack, biasP, bias2);

    // fused QKV projection, all batches: [eeg|pps](8192x256 fp32) @ Wpack(256x768 bf16) + bias -> Y (bf16)
    gemm_bias_kernel<false, false><<<dim3(12, 128, 2), 256, 0, stream>>>(
        eeg, pps, Wpack, Wpack + 196608, biasP, biasP + 768,
        Y, Y + 8192 * 768, 768);

    // windowed attention, all batches -> att (bf16, [dir][8192][256])
    attn_kernel<<<dim3(2048 / ATT_TS, 4, 2), 256, 0, stream>>>(Y, biasP, att);

    // output projection: att(bf16) @ Wo(bf16) + bo -> d_out (fp32)
    gemm_bias_kernel<true, true><<<dim3(4, 128, 2), 256, 0, stream>>>(
        att, att + 8192 * 256, Wopack, Wopack + 65536, bias2, bias2 + 256,
        out, out + 2097152, 256);
}

// Round 5
// 193.761 us; speedup vs baseline: 2.7411x; 1.2133x over previous
//
#include <hip/hip_runtime.h>

// ---------- helpers ----------
static __device__ __forceinline__ float bf2f(unsigned short u) {
    return __uint_as_float(((unsigned int)u) << 16);
}
static __device__ __forceinline__ unsigned short f2bf(float f) {
    unsigned int x = __float_as_uint(f);
    unsigned int lsb = (x >> 16) & 1u;
    x += 0x7fffu + lsb;                 // round-to-nearest-even
    return (unsigned short)(x >> 16);
}

typedef __attribute__((ext_vector_type(8))) short short8;    // 8 bf16 = 4 VGPRs (MFMA A/B frag)
typedef __attribute__((ext_vector_type(4))) float floatx4;   // MFMA C/D frag

// ---------- repack: fp32 weights -> bf16 TRANSPOSED packs + fp32 biases ----------
// Wpack_t[inp][n][k] (n=proj*256+h*32+e, k=0..255); inp0=[e2p_Wq|p2e_Wk|p2e_Wv], inp1=[p2e_Wq|e2p_Wk|e2p_Wv]
// Wopack_t[dir][n][k] = Wo[k][n] ; bias_pack[inp][768] fp32 ; bias2[dir][256] fp32
__global__ __launch_bounds__(256) void repack_kernel(
    const float* e2p_Wq, const float* e2p_bq,
    const float* e2p_Wk, const float* e2p_bk,
    const float* e2p_Wv, const float* e2p_bv,
    const float* e2p_Wo, const float* e2p_bo,
    const float* p2e_Wq, const float* p2e_bq,
    const float* p2e_Wk, const float* p2e_bk,
    const float* p2e_Wv, const float* p2e_bv,
    const float* p2e_Wo, const float* p2e_bo,
    unsigned short* Wpack, unsigned short* Wopack, float* bias_pack, float* bias2)
{
    int idx = blockIdx.x * 256 + threadIdx.x;
    const int WP = 2 * 768 * 256;
    if (idx < WP) {
        int inp = idx / (768 * 256);
        int rem = idx % (768 * 256);
        int n = rem / 256, k = rem % 256;
        int proj = n / 256, h = (n % 256) / 32, e = n % 32;
        const float* W;
        if (inp == 0) W = (proj == 0) ? e2p_Wq : (proj == 1) ? p2e_Wk : p2e_Wv;
        else          W = (proj == 0) ? p2e_Wq : (proj == 1) ? e2p_Wk : e2p_Wv;
        Wpack[idx] = f2bf(W[h * 8192 + k * 32 + e]);   // W[h][d=k][e], strides (8192,32,1)
    }
    int idx2 = idx - WP;
    if (idx2 >= 0 && idx2 < 2 * 65536) {
        int dir = idx2 / 65536, rem2 = idx2 % 65536;
        int n = rem2 / 256, k = rem2 % 256;
        Wopack[idx2] = f2bf((dir == 0 ? e2p_Wo : p2e_Wo)[k * 256 + n]);   // transposed
    }
    if (idx < 1536) {
        int inp = idx / 768, n = idx % 768;
        int proj = n / 256, he = n % 256;
        const float* bsrc;
        if (inp == 0) bsrc = (proj == 0) ? e2p_bq : (proj == 1) ? p2e_bk : p2e_bv;
        else          bsrc = (proj == 0) ? p2e_bq : (proj == 1) ? e2p_bk : e2p_bv;
        bias_pack[idx] = bsrc[he];
    }
    if (idx >= 1536 && idx < 2048) {
        int j = idx - 1536;
        int dir = j / 256, n = j % 256;
        bias2[j] = (dir == 0 ? e2p_bo : p2e_bo)[n];
    }
}

// ---------- convert: eeg/pps fp32 -> bf16 activations (done once; GEMM reads bf16) ----------
__global__ __launch_bounds__(256) void convert_kernel(
    const float* __restrict__ eeg, const float* __restrict__ pps,
    unsigned short* __restrict__ Abf)
{
    const int inp = blockIdx.y;
    const float* src = inp ? pps : eeg;
    long base = ((long)blockIdx.x * 256 + threadIdx.x) * 8;
    float v[8];
    __builtin_memcpy(v, src + base, 32);
    unsigned short o[8];
    #pragma unroll
    for (int j = 0; j < 8; ++j) o[j] = f2bf(v[j]);
    __builtin_memcpy(Abf + (long)inp * 2097152 + base, o, 16);
}

// ---------- MFMA GEMM: C[8192 x N] = A(8192 x 256 bf16) @ Bt^T + bias ----------
// Bt is B transposed: [N][256] bf16. 128x128 tile, 4 waves x (64x64 quadrant = 4x4 MFMAs),
// BK=64 (2 mfma-K per chunk), K=256 -> 4 chunks. Epilogue routes C through LDS for
// coalesced stores. C dtype: bf16 (QKV->Y) or fp32 (final output).
template<bool C_F32>
__global__ __launch_bounds__(256) void mfma_gemm_kernel(
    const unsigned short* __restrict__ A0, const unsigned short* __restrict__ A1,
    const unsigned short* __restrict__ B0t, const unsigned short* __restrict__ B1t,
    const float* __restrict__ bias0, const float* __restrict__ bias1,
    void* __restrict__ C0v, void* __restrict__ C1v,
    int N)
{
    __shared__ __align__(16) unsigned short smem[18432];   // 36864 B
    unsigned short (*As)[72] = (unsigned short(*)[72])smem;            // 128 x 64 (+8 pad)
    unsigned short (*Bs)[72] = (unsigned short(*)[72])(smem + 9216);   // 128 x 64 (+8 pad)

    const int z = blockIdx.z;
    const unsigned short* A = z ? A1 : A0;
    const unsigned short* Bt = z ? B1t : B0t;
    const float* bias = z ? bias1 : bias0;
    void* Cv = z ? C1v : C0v;

    const int tid = threadIdx.x;
    const long m0 = (long)blockIdx.y * 128;
    const int n0 = blockIdx.x * 128;

    // staging: thread -> (row, half of 32 k's)
    const int srow = tid >> 1, shalf = (tid & 1) * 32;
    const unsigned short* Arow = A + (m0 + srow) * 256 + shalf;
    const unsigned short* Brow = Bt + (long)(n0 + srow) * 256 + shalf;

    // compute: wave quadrant + fragment indices
    const int lane = tid & 63;
    const int wv = tid >> 6;
    const int wm = (wv >> 1) * 64, wn = (wv & 1) * 64;
    const int fr = lane & 15;            // m (A) / n (B) / col (C)
    const int fq = (lane >> 4) * 8;      // k offset within chunk

    floatx4 acc[4][4] = {};

    for (int kb = 0; kb < 256; kb += 64) {
        uint4 av[2], bv[2];
        __builtin_memcpy(&av[0], Arow + kb, 16);
        __builtin_memcpy(&av[1], Arow + kb + 8, 16);
        __builtin_memcpy(&bv[0], Brow + kb, 16);
        __builtin_memcpy(&bv[1], Brow + kb + 8, 16);
        uint4 av2[2], bv2[2];
        __builtin_memcpy(&av2[0], Arow + kb + 16, 16);
        __builtin_memcpy(&av2[1], Arow + kb + 24, 16);
        __builtin_memcpy(&bv2[0], Brow + kb + 16, 16);
        __builtin_memcpy(&bv2[1], Brow + kb + 24, 16);
        __syncthreads();   // all waves done reading previous chunk
        __builtin_memcpy(&As[srow][shalf + 0], &av[0], 16);
        __builtin_memcpy(&As[srow][shalf + 8], &av[1], 16);
        __builtin_memcpy(&As[srow][shalf + 16], &av2[0], 16);
        __builtin_memcpy(&As[srow][shalf + 24], &av2[1], 16);
        __builtin_memcpy(&Bs[srow][shalf + 0], &bv[0], 16);
        __builtin_memcpy(&Bs[srow][shalf + 8], &bv[1], 16);
        __builtin_memcpy(&Bs[srow][shalf + 16], &bv2[0], 16);
        __builtin_memcpy(&Bs[srow][shalf + 24], &bv2[1], 16);
        __syncthreads();
        #pragma unroll
        for (int kk = 0; kk < 64; kk += 32) {
            short8 af[4], bf_[4];
            #pragma unroll
            for (int i = 0; i < 4; ++i)
                af[i] = *(const short8*)&As[wm + i * 16 + fr][kk + fq];
            #pragma unroll
            for (int j = 0; j < 4; ++j)
                bf_[j] = *(const short8*)&Bs[wn + j * 16 + fr][kk + fq];
            #pragma unroll
            for (int i = 0; i < 4; ++i)
                #pragma unroll
                for (int j = 0; j < 4; ++j)
                    acc[i][j] = __builtin_amdgcn_mfma_f32_16x16x32_bf16(af[i], bf_[j], acc[i][j], 0, 0, 0);
        }
    }

    // ---- epilogue: acc + bias -> bf16 -> LDS -> coalesced global stores ----
    __syncthreads();   // LDS reuse: all ds_reads of As/Bs complete
    unsigned short (*Cs)[136] = (unsigned short(*)[136])smem;   // 128 x 136 = 34816 B

    float bj[4];
    #pragma unroll
    for (int j = 0; j < 4; ++j) bj[j] = bias[n0 + wn + j * 16 + fr];

    const int cr0 = wm + ((lane >> 4) << 2);
    #pragma unroll
    for (int i = 0; i < 4; ++i)
        #pragma unroll
        for (int j = 0; j < 4; ++j)
            #pragma unroll
            for (int r = 0; r < 4; ++r)
                Cs[cr0 + i * 16 + r][wn + j * 16 + fr] = f2bf(acc[i][j][r] + bj[j]);
    __syncthreads();

    const int rr = tid >> 4, cc = (tid & 15) * 8;
    #pragma unroll
    for (int p = 0; p < 8; ++p) {
        int r = p * 16 + rr;
        unsigned short tmp[8];
        __builtin_memcpy(tmp, &Cs[r][cc], 16);
        if (C_F32) {
            float of[8];
            #pragma unroll
            for (int j = 0; j < 8; ++j) of[j] = bf2f(tmp[j]);
            __builtin_memcpy((float*)Cv + (m0 + r) * N + n0 + cc, of, 32);
        } else {
            __builtin_memcpy((unsigned short*)Cv + (m0 + r) * N + n0 + cc, tmp, 16);
        }
    }
}

// ---------- windowed cross-attention, register-resident, all batches ----------
// Y[inp][8192][768]: [0:256]=Q, [256:512]=K, [512:768]=V (bf16), rows m = b*2048+s.
// Block = (s_tile of 32, b, dir); 256 threads = 32 s x 8 h. Each thread owns one (s,h).
// OOB window positions use bias vectors (bk/bv), NOT masked (reference pads kv BEFORE projection).
#define ATT_TS 32
#define ATT_ROWS 62            // TS + 30
#define ATT_STRIDE 132         // pairs (128 + 4 pad), keeps rows 16B aligned
__global__ __launch_bounds__(256) void attn_kernel(
    const unsigned short* __restrict__ Y, const float* __restrict__ bias_pack,
    unsigned short* __restrict__ att)
{
    __shared__ unsigned int Ks[ATT_ROWS][ATT_STRIDE];
    __shared__ unsigned int Vs[ATT_ROWS][ATT_STRIDE];

    const int s0 = blockIdx.x * ATT_TS;
    const int b = blockIdx.y, dir = blockIdx.z;
    const int kvinp = 1 - dir;
    const int tid = threadIdx.x;

    const float* bkv = bias_pack + kvinp * 768;
    const long kvbase = ((long)kvinp * 8192 + b * 2048) * 768;

    // ---- stage K/V rows [s0-15, s0+46] ----
    {
        const int c = (tid & 31) * 4;           // pair index within row (4 pairs = 16B)
        for (int r = tid >> 5; r < ATT_ROWS; r += 8) {
            int p = s0 - 15 + r;
            unsigned int kq[4], vq[4];
            if (p >= 0 && p < 2048) {
                __builtin_memcpy(kq, Y + kvbase + (long)p * 768 + 256 + c * 2, 16);
                __builtin_memcpy(vq, Y + kvbase + (long)p * 768 + 512 + c * 2, 16);
            } else {
                unsigned short kb8[8], vb8[8];
                #pragma unroll
                for (int j = 0; j < 8; ++j) kb8[j] = f2bf(bkv[256 + c * 2 + j]);
                #pragma unroll
                for (int j = 0; j < 8; ++j) vb8[j] = f2bf(bkv[512 + c * 2 + j]);
                __builtin_memcpy(kq, kb8, 16);
                __builtin_memcpy(vq, vb8, 16);
            }
            __builtin_memcpy(&Ks[r][c], kq, 16);
            __builtin_memcpy(&Vs[r][c], vq, 16);
        }
    }

    // ---- load q (32 elems) into registers ----
    const int h = tid & 7, sl = tid >> 3;
    float q[32];
    {
        unsigned short qr[32];
        __builtin_memcpy(qr, Y + ((long)dir * 8192 + b * 2048 + s0 + sl) * 768 + h * 32, 64);
        #pragma unroll
        for (int j = 0; j < 32; ++j) q[j] = bf2f(qr[j]);
    }
    __syncthreads();

    // ---- scores ----
    const int hp = h * 16;
    float sc[31];
    for (int w = 0; w < 31; ++w) {
        float dot = 0.f;
        #pragma unroll
        for (int jp = 0; jp < 16; ++jp) {
            unsigned int u = Ks[sl + w][hp + jp];
            dot += q[2 * jp]     * bf2f((unsigned short)(u & 0xffffu));
            dot += q[2 * jp + 1] * bf2f((unsigned short)(u >> 16));
        }
        sc[w] = dot * 0.17677669529663687f;      // 1/sqrt(32)
    }

    // ---- softmax in registers ----
    float mval = sc[0];
    #pragma unroll
    for (int w = 1; w < 31; ++w) mval = fmaxf(mval, sc[w]);
    float psum = 0.f;
    #pragma unroll
    for (int w = 0; w < 31; ++w) { sc[w] = __expf(sc[w] - mval); psum += sc[w]; }

    // ---- PV accumulate ----
    float o[32] = {};
    for (int w = 0; w < 31; ++w) {
        float pw = sc[w];
        #pragma unroll
        for (int jp = 0; jp < 16; ++jp) {
            unsigned int u = Vs[sl + w][hp + jp];
            o[2 * jp]     += pw * bf2f((unsigned short)(u & 0xffffu));
            o[2 * jp + 1] += pw * bf2f((unsigned short)(u >> 16));
        }
    }

    const float rs = 1.f / psum;
    unsigned short ov[32];
    #pragma unroll
    for (int j = 0; j < 32; ++j) ov[j] = f2bf(o[j] * rs);
    __builtin_memcpy(att + ((long)dir * 8192 + b * 2048 + s0 + sl) * 256 + h * 32, ov, 64);
}

// ---------- launch ----------
extern "C" void kernel_launch(void* const* d_in, const int* in_sizes, int n_in,
                              void* d_out, int out_size, void* d_ws, size_t ws_size,
                              hipStream_t stream)
{
    const float* eeg = (const float*)d_in[0];
    const float* pps = (const float*)d_in[1];
    float* out = (float*)d_out;

    char* ws = (char*)d_ws;
    unsigned short* Wpack   = (unsigned short*)(ws + 0);          // 2*768*256 bf16 = 786432 B (transposed)
    unsigned short* Wopack  = (unsigned short*)(ws + 786432);     // 2*65536 bf16   = 262144 B (transposed)
    float*          biasP   = (float*)(ws + 1048576);             // 1536 f32       = 6144 B
    float*          bias2   = (float*)(ws + 1054720);             // 512 f32        = 2048 B
    unsigned short* Y       = (unsigned short*)(ws + 1056768);    // 2*8192*768 bf16 = 25165824 B
    unsigned short* att     = (unsigned short*)(ws + 26222592);   // 2*8192*256 bf16 = 8388608 B
    unsigned short* Abf     = att;   // aliased: Abf dead before attention writes att
    // total: 34,611,200 B (~33 MB) — same footprint as the passing round-4 layout

    repack_kernel<<<2048, 256, 0, stream>>>(
        (const float*)d_in[2],  (const float*)d_in[3],
        (const float*)d_in[4],  (const float*)d_in[5],
        (const float*)d_in[6],  (const float*)d_in[7],
        (const float*)d_in[8],  (const float*)d_in[9],
        (const float*)d_in[10], (const float*)d_in[11],
        (const float*)d_in[12], (const float*)d_in[13],
        (const float*)d_in[14], (const float*)d_in[15],
        (const float*)d_in[16], (const float*)d_in[17],
        Wpack, Wopack, biasP, bias2);

    // fp32 -> bf16 activations (once)
    convert_kernel<<<dim3(1024, 2), 256, 0, stream>>>(eeg, pps, Abf);

    // fused QKV projection: Abf(8192x256) @ Wpack_t^T (768x256) + bias -> Y (bf16)
    mfma_gemm_kernel<false><<<dim3(6, 64, 2), 256, 0, stream>>>(
        Abf, Abf + 2097152, Wpack, Wpack + 196608, biasP, biasP + 768,
        Y, Y + 8192 * 768, 768);

    // windowed attention -> att (bf16, [dir][8192][256]); overwrites Abf (dead)
    attn_kernel<<<dim3(2048 / ATT_TS, 4, 2), 256, 0, stream>>>(Y, biasP, att);

    // output projection: att(8192x256) @ Wopack_t^T (256x256) + bias -> d_out (fp32)
    mfma_gemm_kernel<true><<<dim3(2, 64, 2), 256, 0, stream>>>(
        att, att + 2097152, Wopack, Wopack + 65536, bias2, bias2 + 256,
        out, out + 2097152, 256);
}

// Round 6
// 167.798 us; speedup vs baseline: 3.1652x; 1.1547x over previous
//
#include <hip/hip_runtime.h>

// ---------- helpers ----------
static __device__ __forceinline__ float bf2f(unsigned short u) {
    return __uint_as_float(((unsigned int)u) << 16);
}
static __device__ __forceinline__ unsigned short f2bf(float f) {
    unsigned int x = __float_as_uint(f);
    unsigned int lsb = (x >> 16) & 1u;
    x += 0x7fffu + lsb;                 // round-to-nearest-even
    return (unsigned short)(x >> 16);
}

typedef __attribute__((ext_vector_type(8))) short short8;    // 8 bf16 = 4 VGPRs (MFMA A/B frag)
typedef __attribute__((ext_vector_type(4))) float floatx4;   // MFMA C/D frag

static __device__ __forceinline__ short8 ldg8(const unsigned short* p) {
    short8 v; __builtin_memcpy(&v, p, 16); return v;
}

// ---------- repack: fp32 weights -> bf16 TRANSPOSED packs + fp32 biases ----------
// Wpack_t[inp][n][k] (n=proj*256+h*32+e, k=0..255); inp0=[e2p_Wq|p2e_Wk|p2e_Wv], inp1=[p2e_Wq|e2p_Wk|e2p_Wv]
// Wopack_t[dir][n][k] = Wo[k][n] ; bias_pack[inp][768] fp32 ; bias2[dir][256] fp32
__global__ __launch_bounds__(256) void repack_kernel(
    const float* e2p_Wq, const float* e2p_bq,
    const float* e2p_Wk, const float* e2p_bk,
    const float* e2p_Wv, const float* e2p_bv,
    const float* e2p_Wo, const float* e2p_bo,
    const float* p2e_Wq, const float* p2e_bq,
    const float* p2e_Wk, const float* p2e_bk,
    const float* p2e_Wv, const float* p2e_bv,
    const float* p2e_Wo, const float* p2e_bo,
    unsigned short* Wpack, unsigned short* Wopack, float* bias_pack, float* bias2)
{
    int idx = blockIdx.x * 256 + threadIdx.x;
    const int WP = 2 * 768 * 256;
    if (idx < WP) {
        int inp = idx / (768 * 256);
        int rem = idx % (768 * 256);
        int n = rem / 256, k = rem % 256;
        int proj = n / 256, h = (n % 256) / 32, e = n % 32;
        const float* W;
        if (inp == 0) W = (proj == 0) ? e2p_Wq : (proj == 1) ? p2e_Wk : p2e_Wv;
        else          W = (proj == 0) ? p2e_Wq : (proj == 1) ? e2p_Wk : e2p_Wv;
        Wpack[idx] = f2bf(W[h * 8192 + k * 32 + e]);   // W[h][d=k][e], strides (8192,32,1)
    }
    int idx2 = idx - WP;
    if (idx2 >= 0 && idx2 < 2 * 65536) {
        int dir = idx2 / 65536, rem2 = idx2 % 65536;
        int n = rem2 / 256, k = rem2 % 256;
        Wopack[idx2] = f2bf((dir == 0 ? e2p_Wo : p2e_Wo)[k * 256 + n]);   // transposed
    }
    if (idx < 1536) {
        int inp = idx / 768, n = idx % 768;
        int proj = n / 256, he = n % 256;
        const float* bsrc;
        if (inp == 0) bsrc = (proj == 0) ? e2p_bq : (proj == 1) ? p2e_bk : p2e_bv;
        else          bsrc = (proj == 0) ? p2e_bq : (proj == 1) ? e2p_bk : e2p_bv;
        bias_pack[idx] = bsrc[he];
    }
    if (idx >= 1536 && idx < 2048) {
        int j = idx - 1536;
        int dir = j / 256, n = j % 256;
        bias2[j] = (dir == 0 ? e2p_bo : p2e_bo)[n];
    }
}

// ---------- convert: eeg/pps fp32 -> bf16 activations (done once; GEMM reads bf16) ----------
__global__ __launch_bounds__(256) void convert_kernel(
    const float* __restrict__ eeg, const float* __restrict__ pps,
    unsigned short* __restrict__ Abf)
{
    const int inp = blockIdx.y;
    const float* src = inp ? pps : eeg;
    long base = ((long)blockIdx.x * 256 + threadIdx.x) * 8;
    float v[8];
    __builtin_memcpy(v, src + base, 32);
    unsigned short o[8];
    #pragma unroll
    for (int j = 0; j < 8; ++j) o[j] = f2bf(v[j]);
    __builtin_memcpy(Abf + (long)inp * 2097152 + base, o, 16);
}

// ---------- MFMA GEMM, barrier-free K-loop ----------
// C[8192 x N] = A(8192 x 256 bf16) @ Bt^T + bias. Bt = B transposed [N][256].
// 128x128 tile, 4 waves in 2x2 quadrant grid (64x64 each, 4x4 MFMAs).
// Fragments loaded DIRECTLY global->VGPR (no LDS staging, no K-loop barriers),
// 2-deep register double-buffer. LDS used only for the coalescing epilogue.
// grid: (m_tiles, n_tiles, input).
template<bool C_F32>
__global__ __launch_bounds__(256) void mfma_gemm_kernel(
    const unsigned short* __restrict__ A0, const unsigned short* __restrict__ A1,
    const unsigned short* __restrict__ B0t, const unsigned short* __restrict__ B1t,
    const float* __restrict__ bias0, const float* __restrict__ bias1,
    void* __restrict__ C0v, void* __restrict__ C1v,
    int N)
{
    __shared__ __align__(16) unsigned short Cs[128][136];   // 34816 B, epilogue only

    const int z = blockIdx.z;
    const unsigned short* A = z ? A1 : A0;
    const unsigned short* Bt = z ? B1t : B0t;
    const float* bias = z ? bias1 : bias0;
    void* Cv = z ? C1v : C0v;

    const int tid = threadIdx.x;
    const long m0 = (long)blockIdx.x * 128;
    const int n0 = blockIdx.y * 128;

    const int lane = tid & 63;
    const int wv = tid >> 6;
    const int wm = (wv >> 1) * 64, wn = (wv & 1) * 64;
    const int fr = lane & 15;            // m (A) / n (B) / col (C)
    const int fq = (lane >> 4) * 8;      // k offset within 32-k chunk

    // per-lane fragment base pointers; fragment (i,kc) at + i*16*256 + kc*32
    const unsigned short* Ap = A + (m0 + wm + fr) * 256 + fq;
    const unsigned short* Bp = Bt + (long)(n0 + wn + fr) * 256 + fq;

    floatx4 acc[4][4] = {};
    short8 af[2][4], bf_[2][4];

    #pragma unroll
    for (int i = 0; i < 4; ++i) af[0][i] = ldg8(Ap + i * 4096);
    #pragma unroll
    for (int j = 0; j < 4; ++j) bf_[0][j] = ldg8(Bp + j * 4096);

    #pragma unroll
    for (int kc = 0; kc < 8; ++kc) {
        const int cur = kc & 1, nxt = cur ^ 1;
        if (kc < 7) {
            const int ko = (kc + 1) * 32;
            #pragma unroll
            for (int i = 0; i < 4; ++i) af[nxt][i] = ldg8(Ap + ko + i * 4096);
            #pragma unroll
            for (int j = 0; j < 4; ++j) bf_[nxt][j] = ldg8(Bp + ko + j * 4096);
        }
        #pragma unroll
        for (int i = 0; i < 4; ++i)
            #pragma unroll
            for (int j = 0; j < 4; ++j)
                acc[i][j] = __builtin_amdgcn_mfma_f32_16x16x32_bf16(af[cur][i], bf_[cur][j], acc[i][j], 0, 0, 0);
    }

    // ---- epilogue: acc + bias -> bf16 -> LDS -> coalesced global stores ----
    float bj[4];
    #pragma unroll
    for (int j = 0; j < 4; ++j) bj[j] = bias[n0 + wn + j * 16 + fr];

    const int cr0 = wm + ((lane >> 4) << 2);
    #pragma unroll
    for (int i = 0; i < 4; ++i)
        #pragma unroll
        for (int j = 0; j < 4; ++j)
            #pragma unroll
            for (int r = 0; r < 4; ++r)
                Cs[cr0 + i * 16 + r][wn + j * 16 + fr] = f2bf(acc[i][j][r] + bj[j]);
    __syncthreads();

    const int rr = tid >> 4, cc = (tid & 15) * 8;
    #pragma unroll
    for (int p = 0; p < 8; ++p) {
        int r = p * 16 + rr;
        unsigned short tmp[8];
        __builtin_memcpy(tmp, &Cs[r][cc], 16);
        if (C_F32) {
            float of[8];
            #pragma unroll
            for (int j = 0; j < 8; ++j) of[j] = bf2f(tmp[j]);
            __builtin_memcpy((float*)Cv + (m0 + r) * N + n0 + cc, of, 32);
        } else {
            __builtin_memcpy((unsigned short*)Cv + (m0 + r) * N + n0 + cc, tmp, 16);
        }
    }
}

// ---------- windowed cross-attention, register-resident, all batches ----------
// Y[inp][8192][768]: [0:256]=Q, [256:512]=K, [512:768]=V (bf16), rows m = b*2048+s.
// Block = (s_tile of 32, b, dir); 256 threads = 32 s x 8 h. Each thread owns one (s,h).
// OOB window positions use bias vectors (bk/bv), NOT masked (reference pads kv BEFORE projection).
#define ATT_TS 32
#define ATT_ROWS 62            // TS + 30
#define ATT_STRIDE 132         // pairs (128 + 4 pad), keeps rows 16B aligned
__global__ __launch_bounds__(256) void attn_kernel(
    const unsigned short* __restrict__ Y, const float* __restrict__ bias_pack,
    unsigned short* __restrict__ att)
{
    __shared__ unsigned int Ks[ATT_ROWS][ATT_STRIDE];
    __shared__ unsigned int Vs[ATT_ROWS][ATT_STRIDE];

    const int s0 = blockIdx.x * ATT_TS;
    const int b = blockIdx.y, dir = blockIdx.z;
    const int kvinp = 1 - dir;
    const int tid = threadIdx.x;

    const float* bkv = bias_pack + kvinp * 768;
    const long kvbase = ((long)kvinp * 8192 + b * 2048) * 768;

    // ---- stage K/V rows [s0-15, s0+46] ----
    {
        const int c = (tid & 31) * 4;           // pair index within row (4 pairs = 16B)
        for (int r = tid >> 5; r < ATT_ROWS; r += 8) {
            int p = s0 - 15 + r;
            unsigned int kq[4], vq[4];
            if (p >= 0 && p < 2048) {
                __builtin_memcpy(kq, Y + kvbase + (long)p * 768 + 256 + c * 2, 16);
                __builtin_memcpy(vq, Y + kvbase + (long)p * 768 + 512 + c * 2, 16);
            } else {
                unsigned short kb8[8], vb8[8];
                #pragma unroll
                for (int j = 0; j < 8; ++j) kb8[j] = f2bf(bkv[256 + c * 2 + j]);
                #pragma unroll
                for (int j = 0; j < 8; ++j) vb8[j] = f2bf(bkv[512 + c * 2 + j]);
                __builtin_memcpy(kq, kb8, 16);
                __builtin_memcpy(vq, vb8, 16);
            }
            __builtin_memcpy(&Ks[r][c], kq, 16);
            __builtin_memcpy(&Vs[r][c], vq, 16);
        }
    }

    // ---- load q (32 elems) into registers ----
    const int h = tid & 7, sl = tid >> 3;
    float q[32];
    {
        unsigned short qr[32];
        __builtin_memcpy(qr, Y + ((long)dir * 8192 + b * 2048 + s0 + sl) * 768 + h * 32, 64);
        #pragma unroll
        for (int j = 0; j < 32; ++j) q[j] = bf2f(qr[j]);
    }
    __syncthreads();

    // ---- scores ----
    const int hp = h * 16;
    float sc[31];
    for (int w = 0; w < 31; ++w) {
        float dot = 0.f;
        #pragma unroll
        for (int jp = 0; jp < 16; ++jp) {
            unsigned int u = Ks[sl + w][hp + jp];
            dot += q[2 * jp]     * bf2f((unsigned short)(u & 0xffffu));
            dot += q[2 * jp + 1] * bf2f((unsigned short)(u >> 16));
        }
        sc[w] = dot * 0.17677669529663687f;      // 1/sqrt(32)
    }

    // ---- softmax in registers ----
    float mval = sc[0];
    #pragma unroll
    for (int w = 1; w < 31; ++w) mval = fmaxf(mval, sc[w]);
    float psum = 0.f;
    #pragma unroll
    for (int w = 0; w < 31; ++w) { sc[w] = __expf(sc[w] - mval); psum += sc[w]; }

    // ---- PV accumulate ----
    float o[32] = {};
    for (int w = 0; w < 31; ++w) {
        float pw = sc[w];
        #pragma unroll
        for (int jp = 0; jp < 16; ++jp) {
            unsigned int u = Vs[sl + w][hp + jp];
            o[2 * jp]     += pw * bf2f((unsigned short)(u & 0xffffu));
            o[2 * jp + 1] += pw * bf2f((unsigned short)(u >> 16));
        }
    }

    const float rs = 1.f / psum;
    unsigned short ov[32];
    #pragma unroll
    for (int j = 0; j < 32; ++j) ov[j] = f2bf(o[j] * rs);
    __builtin_memcpy(att + ((long)dir * 8192 + b * 2048 + s0 + sl) * 256 + h * 32, ov, 64);
}

// ---------- launch ----------
extern "C" void kernel_launch(void* const* d_in, const int* in_sizes, int n_in,
                              void* d_out, int out_size, void* d_ws, size_t ws_size,
                              hipStream_t stream)
{
    const float* eeg = (const float*)d_in[0];
    const float* pps = (const float*)d_in[1];
    float* out = (float*)d_out;

    char* ws = (char*)d_ws;
    unsigned short* Wpack   = (unsigned short*)(ws + 0);          // 2*768*256 bf16 = 786432 B (transposed)
    unsigned short* Wopack  = (unsigned short*)(ws + 786432);     // 2*65536 bf16   = 262144 B (transposed)
    float*          biasP   = (float*)(ws + 1048576);             // 1536 f32       = 6144 B
    float*          bias2   = (float*)(ws + 1054720);             // 512 f32        = 2048 B
    unsigned short* Y       = (unsigned short*)(ws + 1056768);    // 2*8192*768 bf16 = 25165824 B
    unsigned short* att     = (unsigned short*)(ws + 26222592);   // 2*8192*256 bf16 = 8388608 B
    unsigned short* Abf     = att;   // aliased: Abf dead before attention writes att
    // total: 34,611,200 B (~33 MB)

    repack_kernel<<<2048, 256, 0, stream>>>(
        (const float*)d_in[2],  (const float*)d_in[3],
        (const float*)d_in[4],  (const float*)d_in[5],
        (const float*)d_in[6],  (const float*)d_in[7],
        (const float*)d_in[8],  (const float*)d_in[9],
        (const float*)d_in[10], (const float*)d_in[11],
        (const float*)d_in[12], (const float*)d_in[13],
        (const float*)d_in[14], (const float*)d_in[15],
        (const float*)d_in[16], (const float*)d_in[17],
        Wpack, Wopack, biasP, bias2);

    // fp32 -> bf16 activations (once)
    convert_kernel<<<dim3(1024, 2), 256, 0, stream>>>(eeg, pps, Abf);

    // fused QKV projection: Abf(8192x256) @ Wpack_t^T (768x256) + bias -> Y (bf16)
    mfma_gemm_kernel<false><<<dim3(64, 6, 2), 256, 0, stream>>>(
        Abf, Abf + 2097152, Wpack, Wpack + 196608, biasP, biasP + 768,
        Y, Y + 8192 * 768, 768);

    // windowed attention -> att (bf16, [dir][8192][256]); overwrites Abf (dead)
    attn_kernel<<<dim3(2048 / ATT_TS, 4, 2), 256, 0, stream>>>(Y, biasP, att);

    // output projection: att(8192x256) @ Wopack_t^T (256x256) + bias -> d_out (fp32)
    mfma_gemm_kernel<true><<<dim3(64, 2, 2), 256, 0, stream>>>(
        att, att + 2097152, Wopack, Wopack + 65536, bias2, bias2 + 256,
        out, out + 2097152, 256);
}

// Round 7
// 157.603 us; speedup vs baseline: 3.3700x; 1.0647x over previous
//
#include <hip/hip_runtime.h>

// ---------- helpers ----------
static __device__ __forceinline__ float bf2f(unsigned short u) {
    return __uint_as_float(((unsigned int)u) << 16);
}
static __device__ __forceinline__ unsigned short f2bf(float f) {
    unsigned int x = __float_as_uint(f);
    unsigned int lsb = (x >> 16) & 1u;
    x += 0x7fffu + lsb;                 // round-to-nearest-even
    return (unsigned short)(x >> 16);
}

typedef __attribute__((ext_vector_type(8))) short short8;    // 8 bf16 = 4 VGPRs (MFMA A/B frag)
typedef __attribute__((ext_vector_type(4))) float floatx4;   // MFMA C/D frag

static __device__ __forceinline__ short8 ldg8(const unsigned short* p) {
    short8 v; __builtin_memcpy(&v, p, 16); return v;
}

// ---------- repack + convert (fused): weights -> bf16 transposed packs, activations -> bf16 ----------
// Wpack_t[inp][n][k] (n=proj*256+h*32+e); inp0=[e2p_Wq|p2e_Wk|p2e_Wv], inp1=[p2e_Wq|e2p_Wk|e2p_Wv]
// Wopack_t[dir][n][k] = Wo[k][n] ; bias_pack[inp][768] fp32 ; bias2[dir][256] fp32 ; Abf = bf16(eeg|pps)
__global__ __launch_bounds__(256) void repack_kernel(
    const float* e2p_Wq, const float* e2p_bq,
    const float* e2p_Wk, const float* e2p_bk,
    const float* e2p_Wv, const float* e2p_bv,
    const float* e2p_Wo, const float* e2p_bo,
    const float* p2e_Wq, const float* p2e_bq,
    const float* p2e_Wk, const float* p2e_bk,
    const float* p2e_Wv, const float* p2e_bv,
    const float* p2e_Wo, const float* p2e_bo,
    const float* eeg, const float* pps,
    unsigned short* Wpack, unsigned short* Wopack, float* bias_pack, float* bias2,
    unsigned short* Abf)
{
    int idx = blockIdx.x * 256 + threadIdx.x;
    const int WP = 2 * 768 * 256;
    if (idx < WP) {
        int inp = idx / (768 * 256);
        int rem = idx % (768 * 256);
        int n = rem / 256, k = rem % 256;
        int proj = n / 256, h = (n % 256) / 32, e = n % 32;
        const float* W;
        if (inp == 0) W = (proj == 0) ? e2p_Wq : (proj == 1) ? p2e_Wk : p2e_Wv;
        else          W = (proj == 0) ? p2e_Wq : (proj == 1) ? e2p_Wk : e2p_Wv;
        Wpack[idx] = f2bf(W[h * 8192 + k * 32 + e]);   // W[h][d=k][e], strides (8192,32,1)
    }
    int idx2 = idx - WP;
    if (idx2 >= 0 && idx2 < 2 * 65536) {
        int dir = idx2 / 65536, rem2 = idx2 % 65536;
        int n = rem2 / 256, k = rem2 % 256;
        Wopack[idx2] = f2bf((dir == 0 ? e2p_Wo : p2e_Wo)[k * 256 + n]);   // transposed
    }
    if (idx < 1536) {
        int inp = idx / 768, n = idx % 768;
        int proj = n / 256, he = n % 256;
        const float* bsrc;
        if (inp == 0) bsrc = (proj == 0) ? e2p_bq : (proj == 1) ? p2e_bk : p2e_bv;
        else          bsrc = (proj == 0) ? p2e_bq : (proj == 1) ? e2p_bk : e2p_bv;
        bias_pack[idx] = bsrc[he];
    }
    if (idx >= 1536 && idx < 2048) {
        int j = idx - 1536;
        int dir = j / 256, n = j % 256;
        bias2[j] = (dir == 0 ? e2p_bo : p2e_bo)[n];
    }
    // convert: 524288 threads x 8 floats = 4.19M elems = eeg(2.1M) + pps(2.1M)
    {
        long base = (long)idx * 8;
        const float* src = (base < 2097152) ? eeg : pps;
        long off = (base < 2097152) ? base : base - 2097152;
        float v[8];
        __builtin_memcpy(v, src + off, 32);
        unsigned short o[8];
        #pragma unroll
        for (int j = 0; j < 8; ++j) o[j] = f2bf(v[j]);
        __builtin_memcpy(Abf + base, o, 16);
    }
}

// ---------- MFMA GEMM, barrier-free K-loop (unchanged from round 6) ----------
template<bool C_F32>
__global__ __launch_bounds__(256) void mfma_gemm_kernel(
    const unsigned short* __restrict__ A0, const unsigned short* __restrict__ A1,
    const unsigned short* __restrict__ B0t, const unsigned short* __restrict__ B1t,
    const float* __restrict__ bias0, const float* __restrict__ bias1,
    void* __restrict__ C0v, void* __restrict__ C1v,
    int N)
{
    __shared__ __align__(16) unsigned short Cs[128][136];   // epilogue only

    const int z = blockIdx.z;
    const unsigned short* A = z ? A1 : A0;
    const unsigned short* Bt = z ? B1t : B0t;
    const float* bias = z ? bias1 : bias0;
    void* Cv = z ? C1v : C0v;

    const int tid = threadIdx.x;
    const long m0 = (long)blockIdx.x * 128;
    const int n0 = blockIdx.y * 128;

    const int lane = tid & 63;
    const int wv = tid >> 6;
    const int wm = (wv >> 1) * 64, wn = (wv & 1) * 64;
    const int fr = lane & 15;
    const int fq = (lane >> 4) * 8;

    const unsigned short* Ap = A + (m0 + wm + fr) * 256 + fq;
    const unsigned short* Bp = Bt + (long)(n0 + wn + fr) * 256 + fq;

    floatx4 acc[4][4] = {};
    short8 af[2][4], bf_[2][4];

    #pragma unroll
    for (int i = 0; i < 4; ++i) af[0][i] = ldg8(Ap + i * 4096);
    #pragma unroll
    for (int j = 0; j < 4; ++j) bf_[0][j] = ldg8(Bp + j * 4096);

    #pragma unroll
    for (int kc = 0; kc < 8; ++kc) {
        const int cur = kc & 1, nxt = cur ^ 1;
        if (kc < 7) {
            const int ko = (kc + 1) * 32;
            #pragma unroll
            for (int i = 0; i < 4; ++i) af[nxt][i] = ldg8(Ap + ko + i * 4096);
            #pragma unroll
            for (int j = 0; j < 4; ++j) bf_[nxt][j] = ldg8(Bp + ko + j * 4096);
        }
        #pragma unroll
        for (int i = 0; i < 4; ++i)
            #pragma unroll
            for (int j = 0; j < 4; ++j)
                acc[i][j] = __builtin_amdgcn_mfma_f32_16x16x32_bf16(af[cur][i], bf_[cur][j], acc[i][j], 0, 0, 0);
    }

    float bj[4];
    #pragma unroll
    for (int j = 0; j < 4; ++j) bj[j] = bias[n0 + wn + j * 16 + fr];

    const int cr0 = wm + ((lane >> 4) << 2);
    #pragma unroll
    for (int i = 0; i < 4; ++i)
        #pragma unroll
        for (int j = 0; j < 4; ++j)
            #pragma unroll
            for (int r = 0; r < 4; ++r)
                Cs[cr0 + i * 16 + r][wn + j * 16 + fr] = f2bf(acc[i][j][r] + bj[j]);
    __syncthreads();

    const int rr = tid >> 4, cc = (tid & 15) * 8;
    #pragma unroll
    for (int p = 0; p < 8; ++p) {
        int r = p * 16 + rr;
        unsigned short tmp[8];
        __builtin_memcpy(tmp, &Cs[r][cc], 16);
        if (C_F32) {
            float of[8];
            #pragma unroll
            for (int j = 0; j < 8; ++j) of[j] = bf2f(tmp[j]);
            __builtin_memcpy((float*)Cv + (m0 + r) * N + n0 + cc, of, 32);
        } else {
            __builtin_memcpy((unsigned short*)Cv + (m0 + r) * N + n0 + cc, tmp, 16);
        }
    }
}

// ---------- MFMA windowed cross-attention ----------
// Block = (s-tile of 16, head-group of 4, b*2+dir), 256 thr = 4 waves (1 head each).
// Stage K/V rows [s0-15, s0+48] (64 rows incl. pad; OOB rows = bias vectors, NOT masked —
// reference pads kv BEFORE projection). Scores S[16][64] = Q.K^T via 4 MFMAs (C-layout),
// band mask 0 <= kv - i <= 30, softmax (4 xor-shuffles/row over the 16-lane group),
// P -> LDS bf16 (A-layout round-trip), PV via 4 MFMAs, scale by 1/psum, store.
#define KV_STRIDE 138
#define P_STRIDE 72
__global__ __launch_bounds__(256) void attn_kernel(
    const unsigned short* __restrict__ Y, const float* __restrict__ bias_pack,
    unsigned short* __restrict__ att)
{
    __shared__ unsigned short Ks[64][KV_STRIDE];   // 17664 B
    __shared__ unsigned short Vs[64][KV_STRIDE];   // 17664 B
    __shared__ unsigned short Ps[4][16][P_STRIDE]; //  9216 B   (total ~44.5 KB)

    const int s0 = blockIdx.x * 16;
    const int hg = blockIdx.y;                  // head group: heads hg*4 .. hg*4+3
    const int b = blockIdx.z >> 1, dir = blockIdx.z & 1;
    const int kvinp = 1 - dir;
    const int tid = threadIdx.x;

    const float* bkv = bias_pack + kvinp * 768;
    const long kvbase = ((long)kvinp * 8192 + b * 2048) * 768;

    // ---- stage K/V: 64 rows x 128 e (this head group) ----
    {
        const int r = tid >> 2;                 // 0..63
        const int seg = (tid & 3) * 32;         // e offset within the 128
        const int ebase = hg * 128 + seg;
        int p = s0 - 15 + r;
        unsigned short kr[32], vr[32];
        if (p >= 0 && p < 2048) {
            __builtin_memcpy(kr, Y + kvbase + (long)p * 768 + 256 + ebase, 64);
            __builtin_memcpy(vr, Y + kvbase + (long)p * 768 + 512 + ebase, 64);
        } else {
            #pragma unroll
            for (int j = 0; j < 32; ++j) kr[j] = f2bf(bkv[256 + ebase + j]);
            #pragma unroll
            for (int j = 0; j < 32; ++j) vr[j] = f2bf(bkv[512 + ebase + j]);
        }
        __builtin_memcpy(&Ks[r][seg], kr, 64);
        __builtin_memcpy(&Vs[r][seg], vr, 64);
    }

    // ---- Q fragment (A-layout) direct from global ----
    const int lane = tid & 63;
    const int wv = tid >> 6;                    // head-local index
    const int head = hg * 4 + wv;
    const int fr = lane & 15, q4 = lane >> 4;
    short8 aq = ldg8(Y + ((long)dir * 8192 + b * 2048 + s0 + fr) * 768 + head * 32 + q4 * 8);

    __syncthreads();

    // ---- scores: S[16 s][64 kv] via 4 MFMAs ----
    floatx4 sacc[4] = {};
    #pragma unroll
    for (int kvt = 0; kvt < 4; ++kvt) {
        short8 bk_ = *(const short8*)&Ks[kvt * 16 + fr][wv * 32 + q4 * 8];
        sacc[kvt] = __builtin_amdgcn_mfma_f32_16x16x32_bf16(aq, bk_, sacc[kvt], 0, 0, 0);
    }

    // ---- band mask + softmax (rows i = q4*4+reg owned by this lane's 16-lane group) ----
    float sv[4][4];
    float mx[4] = {-3.0e38f, -3.0e38f, -3.0e38f, -3.0e38f};
    #pragma unroll
    for (int kvt = 0; kvt < 4; ++kvt)
        #pragma unroll
        for (int reg = 0; reg < 4; ++reg) {
            int i = q4 * 4 + reg;
            int jc = kvt * 16 + fr;
            int d = jc - i;
            float x = (d >= 0 && d <= 30) ? sacc[kvt][reg] * 0.17677669529663687f : -3.0e38f;
            sv[kvt][reg] = x;
            mx[reg] = fmaxf(mx[reg], x);
        }
    #pragma unroll
    for (int off = 1; off < 16; off <<= 1)
        #pragma unroll
        for (int reg = 0; reg < 4; ++reg)
            mx[reg] = fmaxf(mx[reg], __shfl_xor(mx[reg], off));
    float ps[4] = {};
    #pragma unroll
    for (int kvt = 0; kvt < 4; ++kvt)
        #pragma unroll
        for (int reg = 0; reg < 4; ++reg) {
            float e = __expf(sv[kvt][reg] - mx[reg]);
            sv[kvt][reg] = e;
            ps[reg] += e;
        }
    #pragma unroll
    for (int off = 1; off < 16; off <<= 1)
        #pragma unroll
        for (int reg = 0; reg < 4; ++reg)
            ps[reg] += __shfl_xor(ps[reg], off);

    // ---- P -> LDS (bf16) ----
    #pragma unroll
    for (int kvt = 0; kvt < 4; ++kvt)
        #pragma unroll
        for (int reg = 0; reg < 4; ++reg)
            Ps[wv][q4 * 4 + reg][kvt * 16 + fr] = f2bf(sv[kvt][reg]);
    __syncthreads();

    // ---- PV: O[16 s][32 e] via 4 MFMAs (A = P from LDS, B = V^T via strided reads) ----
    floatx4 oacc[2] = {};
    #pragma unroll
    for (int ch = 0; ch < 2; ++ch) {
        short8 ap = *(const short8*)&Ps[wv][fr][ch * 32 + q4 * 8];
        #pragma unroll
        for (int et = 0; et < 2; ++et) {
            short8 bv;
            #pragma unroll
            for (int j = 0; j < 8; ++j)
                bv[j] = (short)Vs[ch * 32 + q4 * 8 + j][wv * 32 + et * 16 + fr];
            oacc[et] = __builtin_amdgcn_mfma_f32_16x16x32_bf16(ap, bv, oacc[et], 0, 0, 0);
        }
    }

    // ---- scale by 1/psum, store ----
    float rs[4];
    #pragma unroll
    for (int reg = 0; reg < 4; ++reg) rs[reg] = 1.0f / ps[reg];
    #pragma unroll
    for (int et = 0; et < 2; ++et)
        #pragma unroll
        for (int reg = 0; reg < 4; ++reg) {
            int i = q4 * 4 + reg;
            att[((long)dir * 8192 + b * 2048 + s0 + i) * 256 + head * 32 + et * 16 + fr]
                = f2bf(oacc[et][reg] * rs[reg]);
        }
}

// ---------- launch ----------
extern "C" void kernel_launch(void* const* d_in, const int* in_sizes, int n_in,
                              void* d_out, int out_size, void* d_ws, size_t ws_size,
                              hipStream_t stream)
{
    float* out = (float*)d_out;

    char* ws = (char*)d_ws;
    unsigned short* Wpack   = (unsigned short*)(ws + 0);          // 786432 B (transposed)
    unsigned short* Wopack  = (unsigned short*)(ws + 786432);     // 262144 B (transposed)
    float*          biasP   = (float*)(ws + 1048576);             // 6144 B
    float*          bias2   = (float*)(ws + 1054720);             // 2048 B
    unsigned short* Y       = (unsigned short*)(ws + 1056768);    // 25165824 B
    unsigned short* att     = (unsigned short*)(ws + 26222592);   // 8388608 B
    unsigned short* Abf     = att;   // aliased: Abf dead before attention writes att

    repack_kernel<<<2048, 256, 0, stream>>>(
        (const float*)d_in[2],  (const float*)d_in[3],
        (const float*)d_in[4],  (const float*)d_in[5],
        (const float*)d_in[6],  (const float*)d_in[7],
        (const float*)d_in[8],  (const float*)d_in[9],
        (const float*)d_in[10], (const float*)d_in[11],
        (const float*)d_in[12], (const float*)d_in[13],
        (const float*)d_in[14], (const float*)d_in[15],
        (const float*)d_in[16], (const float*)d_in[17],
        (const float*)d_in[0],  (const float*)d_in[1],
        Wpack, Wopack, biasP, bias2, Abf);

    // fused QKV projection: Abf(8192x256) @ Wpack_t^T (768x256) + bias -> Y (bf16)
    mfma_gemm_kernel<false><<<dim3(64, 6, 2), 256, 0, stream>>>(
        Abf, Abf + 2097152, Wpack, Wpack + 196608, biasP, biasP + 768,
        Y, Y + 8192 * 768, 768);

    // MFMA windowed attention -> att (bf16, [dir][8192][256]); overwrites Abf (dead)
    attn_kernel<<<dim3(128, 2, 8), 256, 0, stream>>>(Y, biasP, att);

    // output projection: att(8192x256) @ Wopack_t^T (256x256) + bias -> d_out (fp32)
    mfma_gemm_kernel<true><<<dim3(64, 2, 2), 256, 0, stream>>>(
        att, att + 2097152, Wopack, Wopack + 65536, bias2, bias2 + 256,
        out, out + 2097152, 256);
}